// Round 1
// baseline (894.818 us; speedup 1.0000x reference)
//
#include <hip/hip_runtime.h>
#include <hip/hip_bf16.h>
#include <cstdint>
#include <cstddef>

// Problem constants (from reference): N=50000 nodes, E=800000 edges,
// IN=HID=256, EMB=PROJ=128.
#define NN 50000
#define NE 800000

// ---------------- degree / normalization ----------------

__global__ void k_init_deg(float* deg, int n) {
    int i = blockIdx.x * blockDim.x + threadIdx.x;
    if (i < n) deg[i] = 1.0f;  // self-loop contributes weight 1
}

// histogram (dst counts) + weighted degree in one pass
__global__ void k_edge_pass1(const int* __restrict__ ecol, const float* __restrict__ eval_,
                             float* __restrict__ deg, int* __restrict__ cnt, int e) {
    int i = blockIdx.x * blockDim.x + threadIdx.x;
    if (i < e) {
        int d = ecol[i];
        atomicAdd(&deg[d], eval_[i]);
        atomicAdd(&cnt[d], 1);
    }
}

__global__ void k_dinv(const float* __restrict__ deg, float* __restrict__ dinv, int n) {
    int i = blockIdx.x * blockDim.x + threadIdx.x;
    if (i < n) {
        float d = deg[i];
        dinv[i] = d > 0.f ? rsqrtf(d) : 0.f;
    }
}

// single-block exclusive scan over cnt[n] -> rowptr[n+1], cur[n]=rowptr[n copy]
__global__ void k_scan(const int* __restrict__ cnt, int* __restrict__ rowptr,
                       int* __restrict__ cur, int n) {
    __shared__ int wsum[4];
    __shared__ int carry_s;
    int tid = threadIdx.x;
    int lane = tid & 63, w = tid >> 6;
    if (tid == 0) carry_s = 0;
    __syncthreads();
    for (int base = 0; base < n; base += 256) {
        int i = base + tid;
        int v = (i < n) ? cnt[i] : 0;
        int incl = v;
#pragma unroll
        for (int d = 1; d < 64; d <<= 1) {
            int t = __shfl_up(incl, d);
            if (lane >= d) incl += t;
        }
        if (lane == 63) wsum[w] = incl;
        __syncthreads();
        int woff = 0;
        for (int j = 0; j < w; ++j) woff += wsum[j];
        int carry = carry_s;
        int ex = carry + woff + incl - v;
        if (i < n) { rowptr[i] = ex; cur[i] = ex; }
        __syncthreads();
        if (tid == 255) carry_s = carry + woff + incl;
        __syncthreads();
    }
    if (tid == 0) rowptr[n] = carry_s;
}

// scatter edges into CSR (by destination), with precomputed normalized weight
__global__ void k_scatter(const int* __restrict__ erow, const int* __restrict__ ecol,
                          const float* __restrict__ eval_, const float* __restrict__ dinv,
                          int* __restrict__ cur, int* __restrict__ esrc,
                          float* __restrict__ ew, int e) {
    int i = blockIdx.x * blockDim.x + threadIdx.x;
    if (i < e) {
        int d = ecol[i], s = erow[i];
        int pos = atomicAdd(&cur[d], 1);
        esrc[pos] = s;
        ew[pos] = dinv[d] * eval_[i] * dinv[s];
    }
}

// ---------------- sparse aggregation ----------------
// out[i,:] = dinv[i]^2 * H[i,:] + sum_j ew[j] * H[esrc[j],:]  (+bias, opt relu)
template<int DIM, bool RELU>
__global__ void k_agg(const float* __restrict__ H, const int* __restrict__ rowptr,
                      const int* __restrict__ esrc, const float* __restrict__ ew,
                      const float* __restrict__ dinv, const float* __restrict__ bias,
                      float* __restrict__ out) {
    int i = blockIdx.x;
    int tid = threadIdx.x;  // DIM threads
    float di = dinv[i];
    float acc = di * di * H[(size_t)i * DIM + tid];
    int beg = rowptr[i], end = rowptr[i + 1];
    __shared__ int s_src[DIM];
    __shared__ float s_w[DIM];
    for (int base = beg; base < end; base += DIM) {
        int m = min(DIM, end - base);
        __syncthreads();
        if (tid < m) { s_src[tid] = esrc[base + tid]; s_w[tid] = ew[base + tid]; }
        __syncthreads();
        for (int j = 0; j < m; ++j)
            acc += s_w[j] * H[(size_t)s_src[j] * DIM + tid];
    }
    float r = acc + bias[tid];
    if (RELU) r = fmaxf(r, 0.f);
    out[(size_t)i * DIM + tid] = r;
}

// ---------------- dense GEMM (fp32, baseline) ----------------
// C[nrows,M] = A[nrows,K] @ W[K,M] (+bias) (opt relu). BM=BN=64, BK=16.
template<bool RELU>
__global__ __launch_bounds__(256) void k_gemm(const float* __restrict__ A,
                                              const float* __restrict__ W,
                                              const float* __restrict__ bias,
                                              float* __restrict__ C,
                                              int nrows, int K, int M) {
    __shared__ float As[16][65];  // [k][m], padded
    __shared__ float Ws[16][64];  // [k][n]
    int tid = threadIdx.x;
    int bm = blockIdx.x * 64;
    int bn = blockIdx.y * 64;
    int tx = tid & 15, ty = tid >> 4;

    float acc[4][4] = {};

    int arow = tid >> 2, ak4 = (tid & 3) * 4;   // A tile: 64 rows x 16 k
    int wk = tid >> 4, wc4 = (tid & 15) * 4;    // W tile: 16 k x 64 cols

    for (int k0 = 0; k0 < K; k0 += 16) {
        int grow = bm + arow;
        float4 av = make_float4(0.f, 0.f, 0.f, 0.f);
        if (grow < nrows)
            av = *reinterpret_cast<const float4*>(&A[(size_t)grow * K + k0 + ak4]);
        As[ak4 + 0][arow] = av.x;
        As[ak4 + 1][arow] = av.y;
        As[ak4 + 2][arow] = av.z;
        As[ak4 + 3][arow] = av.w;
        float4 wv = *reinterpret_cast<const float4*>(&W[(size_t)(k0 + wk) * M + bn + wc4]);
        *reinterpret_cast<float4*>(&Ws[wk][wc4]) = wv;
        __syncthreads();
#pragma unroll
        for (int kk = 0; kk < 16; ++kk) {
            float a[4], b[4];
#pragma unroll
            for (int i = 0; i < 4; ++i) a[i] = As[kk][ty * 4 + i];
#pragma unroll
            for (int j = 0; j < 4; ++j) b[j] = Ws[kk][tx * 4 + j];
#pragma unroll
            for (int i = 0; i < 4; ++i)
#pragma unroll
                for (int j = 0; j < 4; ++j)
                    acc[i][j] += a[i] * b[j];
        }
        __syncthreads();
    }
#pragma unroll
    for (int i = 0; i < 4; ++i) {
        int r = bm + ty * 4 + i;
        if (r >= nrows) continue;
#pragma unroll
        for (int j = 0; j < 4; ++j) {
            int cidx = bn + tx * 4 + j;
            float v = acc[i][j];
            if (bias) v += bias[cidx];
            if (RELU) v = fmaxf(v, 0.f);
            C[(size_t)r * M + cidx] = v;
        }
    }
}

// ---------------- launch ----------------

extern "C" void kernel_launch(void* const* d_in, const int* in_sizes, int n_in,
                              void* d_out, int out_size, void* d_ws, size_t ws_size,
                              hipStream_t stream) {
    const float* x        = (const float*)d_in[0];
    const int*   edge_row = (const int*)d_in[1];
    const int*   edge_col = (const int*)d_in[2];
    const float* edge_val = (const float*)d_in[3];
    const float* W1  = (const float*)d_in[4];
    const float* b1  = (const float*)d_in[5];
    const float* W2  = (const float*)d_in[6];
    const float* b2  = (const float*)d_in[7];
    const float* W3  = (const float*)d_in[8];
    const float* b3  = (const float*)d_in[9];
    const float* P1  = (const float*)d_in[10];
    const float* pb1 = (const float*)d_in[11];
    const float* P2  = (const float*)d_in[12];
    const float* pb2 = (const float*)d_in[13];

    const int N = NN, E = NE;

    // workspace carve-up (256B aligned)
    uintptr_t p = (uintptr_t)d_ws;
    auto alloc = [&](size_t bytes) -> void* {
        void* r = (void*)p;
        p += (bytes + 255) & ~(size_t)255;
        return r;
    };
    float* deg    = (float*)alloc((size_t)N * 4);
    float* dinv   = (float*)alloc((size_t)N * 4);
    int*   cnt    = (int*)alloc((size_t)N * 4);
    int*   rowptr = (int*)alloc((size_t)(N + 1) * 4);
    int*   cur    = (int*)alloc((size_t)N * 4);
    int*   esrc   = (int*)alloc((size_t)E * 4);
    float* ew     = (float*)alloc((size_t)E * 4);
    float* bufA   = (float*)alloc((size_t)N * 256 * 4);
    float* bufB   = (float*)alloc((size_t)N * 256 * 4);

    float* emb = (float*)d_out;                     // N x 128
    float* z   = (float*)d_out + (size_t)N * 128;   // N x 128

    dim3 b256(256);
    dim3 gN((N + 255) / 256);
    dim3 gE((E + 255) / 256);

    // normalization + CSR build
    hipMemsetAsync(cnt, 0, (size_t)N * 4, stream);
    k_init_deg<<<gN, b256, 0, stream>>>(deg, N);
    k_edge_pass1<<<gE, b256, 0, stream>>>(edge_col, edge_val, deg, cnt, E);
    k_dinv<<<gN, b256, 0, stream>>>(deg, dinv, N);
    k_scan<<<1, b256, 0, stream>>>(cnt, rowptr, cur, N);
    k_scatter<<<gE, b256, 0, stream>>>(edge_row, edge_col, edge_val, dinv, cur, esrc, ew, E);

    int gm = (N + 63) / 64;  // 782

    // layer 1: H0 = x @ W1 ; H1 = relu(agg(H0) + b1)
    k_gemm<false><<<dim3(gm, 4), b256, 0, stream>>>(x, W1, nullptr, bufA, N, 256, 256);
    k_agg<256, true><<<dim3(N), dim3(256), 0, stream>>>(bufA, rowptr, esrc, ew, dinv, b1, bufB);

    // layer 2: H2 = H1 @ W2 ; H3 = relu(agg(H2) + b2)
    k_gemm<false><<<dim3(gm, 4), b256, 0, stream>>>(bufB, W2, nullptr, bufA, N, 256, 256);
    k_agg<256, true><<<dim3(N), dim3(256), 0, stream>>>(bufA, rowptr, esrc, ew, dinv, b2, bufB);

    // layer 3: H4 = H3 @ W3 ; emb = agg(H4) + b3
    k_gemm<false><<<dim3(gm, 2), b256, 0, stream>>>(bufB, W3, nullptr, bufA, N, 256, 128);
    k_agg<128, false><<<dim3(N), dim3(128), 0, stream>>>(bufA, rowptr, esrc, ew, dinv, b3, emb);

    // head: z = relu(emb @ P1 + pb1) @ P2 + pb2
    k_gemm<true ><<<dim3(gm, 2), b256, 0, stream>>>(emb, P1, pb1, bufA, N, 128, 128);
    k_gemm<false><<<dim3(gm, 2), b256, 0, stream>>>(bufA, P2, pb2, z, N, 128, 128);
}

// Round 2
// 663.181 us; speedup vs baseline: 1.3493x; 1.3493x over previous
//
#include <hip/hip_runtime.h>
#include <hip/hip_bf16.h>
#include <cstdint>
#include <cstddef>

#define NN 50000
#define NE 800000

typedef __attribute__((ext_vector_type(8))) short bf16x8;
typedef __attribute__((ext_vector_type(4))) float f32x4;

static __device__ __forceinline__ unsigned short f2bf_u(float f) {
    __hip_bfloat16 h = __float2bfloat16(f);
    return *reinterpret_cast<unsigned short*>(&h);
}
static __device__ __forceinline__ float bfu2f(unsigned short u) {
    __hip_bfloat16 h = *reinterpret_cast<__hip_bfloat16*>(&u);
    return __bfloat162float(h);
}

// ---------------- degree / normalization ----------------

__global__ void k_init_deg(float* deg, int n) {
    int i = blockIdx.x * blockDim.x + threadIdx.x;
    if (i < n) deg[i] = 1.0f;  // self-loop weight
}

__global__ void k_edge_pass1(const int* __restrict__ ecol, const float* __restrict__ eval_,
                             float* __restrict__ deg, int* __restrict__ cnt, int e) {
    int i = blockIdx.x * blockDim.x + threadIdx.x;
    if (i < e) {
        int d = ecol[i];
        atomicAdd(&deg[d], eval_[i]);
        atomicAdd(&cnt[d], 1);
    }
}

__global__ void k_dinv(const float* __restrict__ deg, float* __restrict__ dinv, int n) {
    int i = blockIdx.x * blockDim.x + threadIdx.x;
    if (i < n) {
        float d = deg[i];
        dinv[i] = d > 0.f ? rsqrtf(d) : 0.f;
    }
}

// ---------------- multi-block exclusive scan ----------------

__global__ void k_scan_blk(const int* __restrict__ cnt, int* __restrict__ ex,
                           int* __restrict__ bsum, int n) {
    int tid = threadIdx.x;
    int i = blockIdx.x * 256 + tid;
    int v = (i < n) ? cnt[i] : 0;
    int lane = tid & 63, w = tid >> 6;
    int incl = v;
#pragma unroll
    for (int d = 1; d < 64; d <<= 1) {
        int t = __shfl_up(incl, d);
        if (lane >= d) incl += t;
    }
    __shared__ int wsum[4];
    if (lane == 63) wsum[w] = incl;
    __syncthreads();
    int woff = 0;
    for (int j = 0; j < w; ++j) woff += wsum[j];
    if (i < n) ex[i] = woff + incl - v;      // ex may alias cnt (own-index RMW)
    if (tid == 255) bsum[blockIdx.x] = woff + incl;
}

__global__ void k_scan_top(int* __restrict__ bsum, int nb) {
    int tid = threadIdx.x;  // 256 threads, nb <= 256
    int v = (tid < nb) ? bsum[tid] : 0;
    int lane = tid & 63, w = tid >> 6;
    int incl = v;
#pragma unroll
    for (int d = 1; d < 64; d <<= 1) {
        int t = __shfl_up(incl, d);
        if (lane >= d) incl += t;
    }
    __shared__ int wsum[4];
    if (lane == 63) wsum[w] = incl;
    __syncthreads();
    int woff = 0;
    for (int j = 0; j < w; ++j) woff += wsum[j];
    if (tid < nb) bsum[tid] = woff + incl - v;  // exclusive, in place
}

__global__ void k_scan_add(const int* __restrict__ ex, const int* __restrict__ boff,
                           int* __restrict__ rowptr, int* __restrict__ cur, int n, int total) {
    int i = blockIdx.x * 256 + threadIdx.x;
    if (i < n) {
        int v = ex[i] + boff[blockIdx.x];
        rowptr[i] = v;
        cur[i] = v;
    }
    if (i == 0) rowptr[n] = total;
}

// ---------------- CSR scatter ----------------

__global__ void k_scatter(const int* __restrict__ erow, const int* __restrict__ ecol,
                          const float* __restrict__ eval_, const float* __restrict__ dinv,
                          int* __restrict__ cur, int* __restrict__ esrc,
                          float* __restrict__ ew, int e) {
    int i = blockIdx.x * blockDim.x + threadIdx.x;
    if (i < e) {
        int d = ecol[i], s = erow[i];
        int pos = atomicAdd(&cur[d], 1);
        esrc[pos] = s;
        ew[pos] = dinv[d] * eval_[i] * dinv[s];
    }
}

// ---------------- sparse aggregation ----------------
template<int DIM, bool RELU>
__global__ void k_agg(const float* __restrict__ H, const int* __restrict__ rowptr,
                      const int* __restrict__ esrc, const float* __restrict__ ew,
                      const float* __restrict__ dinv, const float* __restrict__ bias,
                      float* __restrict__ out) {
    int i = blockIdx.x;
    int tid = threadIdx.x;  // DIM threads
    float di = dinv[i];
    float acc = di * di * H[(size_t)i * DIM + tid];
    int beg = rowptr[i], end = rowptr[i + 1];
    __shared__ int s_src[DIM];
    __shared__ float s_w[DIM];
    for (int base = beg; base < end; base += DIM) {
        int m = min(DIM, end - base);
        __syncthreads();
        if (tid < m) { s_src[tid] = esrc[base + tid]; s_w[tid] = ew[base + tid]; }
        __syncthreads();
        for (int j = 0; j < m; ++j)
            acc += s_w[j] * H[(size_t)s_src[j] * DIM + tid];
    }
    float r = acc + bias[tid];
    if (RELU) r = fmaxf(r, 0.f);
    out[(size_t)i * DIM + tid] = r;
}

// ---------------- weight pre-split into fragment-ordered hi/lo bf16 ----------------
// layout: [kb=K/32][nb=M/16][kg=4][c=16][kj=8] bf16 (1024B per (kb,nb) chunk)
__global__ void k_wsplit(const float* __restrict__ W, unsigned short* __restrict__ wh,
                         unsigned short* __restrict__ wl, int K, int M) {
    int idx = blockIdx.x * blockDim.x + threadIdx.x;
    if (idx >= K * M) return;
    int k = idx / M, m = idx % M;
    float w = W[idx];
    unsigned short h = f2bf_u(w);
    float hf = bfu2f(h);
    unsigned short lo = f2bf_u(w - hf);
    int kb = k >> 5, kg = (k & 31) >> 3, kj = k & 7;
    int nb = m >> 4, c = m & 15;
    int off = (kb * (M >> 4) + nb) * 512 + kg * 128 + c * 8 + kj;
    wh[off] = h;
    wl[off] = lo;
}

// ---------------- MFMA GEMM: C = A(fp32) @ W (split-bf16, 3-pass) ----------------
// BM x BN tile, BK=32, wave tile 64x64. A converted fp32->hi/lo bf16 in staging,
// written in MFMA fragment order so all ds_read_b128 are wave-contiguous.
template<int BM, int BN, bool RELU>
__global__ __launch_bounds__((BM / 64) * (BN / 64) * 64)
void k_mm(const float* __restrict__ A, const unsigned short* __restrict__ wh,
          const unsigned short* __restrict__ wl, const float* __restrict__ bias,
          float* __restrict__ C, int nrows, int K, int M) {
    constexpr int T = (BM / 64) * (BN / 64) * 64;
    constexpr int WN = BN / 64;
    __shared__ unsigned short Ah[BM * 32], Al[BM * 32], Bh[BN * 32], Bl[BN * 32];
    int tid = threadIdx.x;
    int l = tid & 63;
    int wid = tid >> 6;
    int wr = wid / WN, wc = wid % WN;
    int bm = blockIdx.x * BM, bn = blockIdx.y * BN;
    int nb0 = bn >> 4;
    f32x4 acc[4][4] = {};
    int fo = (l >> 4) * 128 + (l & 15) * 8;  // frag offset in shorts within 512-chunk

    for (int k0 = 0; k0 < K; k0 += 32) {
        int kb = k0 >> 5;
        // stage A: BM x 32 fp32 -> hi/lo bf16, frag-ordered
#pragma unroll
        for (int q = 0; q < 4; ++q) {
            int t2 = tid + q * T;           // 0 .. BM*8-1
            int row = t2 >> 3, kq = t2 & 7;
            int grow = bm + row;
            float4 av = make_float4(0.f, 0.f, 0.f, 0.f);
            if (grow < nrows)
                av = *reinterpret_cast<const float4*>(&A[(size_t)grow * K + k0 + kq * 4]);
            unsigned short h0 = f2bf_u(av.x), h1 = f2bf_u(av.y),
                           h2 = f2bf_u(av.z), h3 = f2bf_u(av.w);
            uint2 hp, lp;
            hp.x = (unsigned)h0 | ((unsigned)h1 << 16);
            hp.y = (unsigned)h2 | ((unsigned)h3 << 16);
            lp.x = (unsigned)f2bf_u(av.x - bfu2f(h0)) | ((unsigned)f2bf_u(av.y - bfu2f(h1)) << 16);
            lp.y = (unsigned)f2bf_u(av.z - bfu2f(h2)) | ((unsigned)f2bf_u(av.w - bfu2f(h3)) << 16);
            int off = (row >> 4) * 512 + (kq >> 1) * 128 + (row & 15) * 8 + (kq & 1) * 4;
            *reinterpret_cast<uint2*>(&Ah[off]) = hp;
            *reinterpret_cast<uint2*>(&Al[off]) = lp;
        }
        // stage B: linear copy of frag-ordered chunks
        const int4* sh = reinterpret_cast<const int4*>(wh) + (size_t)(kb * (M >> 4) + nb0) * 64;
        const int4* sl = reinterpret_cast<const int4*>(wl) + (size_t)(kb * (M >> 4) + nb0) * 64;
        for (int u = tid; u < BN * 4; u += T) {
            *reinterpret_cast<int4*>(&Bh[u * 8]) = sh[u];
            *reinterpret_cast<int4*>(&Bl[u * 8]) = sl[u];
        }
        __syncthreads();
        bf16x8 ah[4], al4[4], bh4[4], bl4[4];
#pragma unroll
        for (int i = 0; i < 4; ++i) {
            ah[i]  = *reinterpret_cast<const bf16x8*>(&Ah[(wr * 4 + i) * 512 + fo]);
            al4[i] = *reinterpret_cast<const bf16x8*>(&Al[(wr * 4 + i) * 512 + fo]);
        }
#pragma unroll
        for (int j = 0; j < 4; ++j) {
            bh4[j] = *reinterpret_cast<const bf16x8*>(&Bh[(wc * 4 + j) * 512 + fo]);
            bl4[j] = *reinterpret_cast<const bf16x8*>(&Bl[(wc * 4 + j) * 512 + fo]);
        }
#pragma unroll
        for (int i = 0; i < 4; ++i)
#pragma unroll
            for (int j = 0; j < 4; ++j) {
                acc[i][j] = __builtin_amdgcn_mfma_f32_16x16x32_bf16(ah[i],  bh4[j], acc[i][j], 0, 0, 0);
                acc[i][j] = __builtin_amdgcn_mfma_f32_16x16x32_bf16(ah[i],  bl4[j], acc[i][j], 0, 0, 0);
                acc[i][j] = __builtin_amdgcn_mfma_f32_16x16x32_bf16(al4[i], bh4[j], acc[i][j], 0, 0, 0);
            }
        __syncthreads();
    }
    // epilogue: D layout col=l&15, row=(l>>4)*4+r
#pragma unroll
    for (int j = 0; j < 4; ++j) {
        int col = bn + wc * 64 + j * 16 + (l & 15);
        float bv = bias ? bias[col] : 0.f;
#pragma unroll
        for (int i = 0; i < 4; ++i) {
            int row0 = bm + wr * 64 + i * 16 + (l >> 4) * 4;
#pragma unroll
            for (int r = 0; r < 4; ++r) {
                int row = row0 + r;
                if (row < nrows) {
                    float v = acc[i][j][r] + bv;
                    if (RELU) v = fmaxf(v, 0.f);
                    C[(size_t)row * M + col] = v;
                }
            }
        }
    }
}

// ---------------- launch ----------------

extern "C" void kernel_launch(void* const* d_in, const int* in_sizes, int n_in,
                              void* d_out, int out_size, void* d_ws, size_t ws_size,
                              hipStream_t stream) {
    const float* x        = (const float*)d_in[0];
    const int*   edge_row = (const int*)d_in[1];
    const int*   edge_col = (const int*)d_in[2];
    const float* edge_val = (const float*)d_in[3];
    const float* W1  = (const float*)d_in[4];
    const float* b1  = (const float*)d_in[5];
    const float* W2  = (const float*)d_in[6];
    const float* b2  = (const float*)d_in[7];
    const float* W3  = (const float*)d_in[8];
    const float* b3  = (const float*)d_in[9];
    const float* P1  = (const float*)d_in[10];
    const float* pb1 = (const float*)d_in[11];
    const float* P2  = (const float*)d_in[12];
    const float* pb2 = (const float*)d_in[13];

    const int N = NN, E = NE;
    const int NB = (N + 255) / 256;  // 196

    uintptr_t p = (uintptr_t)d_ws;
    auto alloc = [&](size_t bytes) -> void* {
        void* r = (void*)p;
        p += (bytes + 255) & ~(size_t)255;
        return r;
    };
    float* deg    = (float*)alloc((size_t)N * 4);
    float* dinv   = (float*)alloc((size_t)N * 4);
    int*   cnt    = (int*)alloc((size_t)N * 4);     // reused as local-exclusive 'ex'
    int*   rowptr = (int*)alloc((size_t)(N + 1) * 4);
    int*   cur    = (int*)alloc((size_t)N * 4);
    int*   bsum   = (int*)alloc(256 * 4);
    int*   esrc   = (int*)alloc((size_t)E * 4);
    float* ew     = (float*)alloc((size_t)E * 4);
    float* bufA   = (float*)alloc((size_t)N * 256 * 4);
    float* bufB   = (float*)alloc((size_t)N * 256 * 4);
    unsigned short* wf1h = (unsigned short*)alloc(65536 * 2);
    unsigned short* wf1l = (unsigned short*)alloc(65536 * 2);
    unsigned short* wf2h = (unsigned short*)alloc(65536 * 2);
    unsigned short* wf2l = (unsigned short*)alloc(65536 * 2);
    unsigned short* wf3h = (unsigned short*)alloc(32768 * 2);
    unsigned short* wf3l = (unsigned short*)alloc(32768 * 2);
    unsigned short* p1h  = (unsigned short*)alloc(16384 * 2);
    unsigned short* p1l  = (unsigned short*)alloc(16384 * 2);
    unsigned short* p2h  = (unsigned short*)alloc(16384 * 2);
    unsigned short* p2l  = (unsigned short*)alloc(16384 * 2);

    float* emb = (float*)d_out;
    float* z   = (float*)d_out + (size_t)N * 128;

    dim3 b256(256);
    dim3 gN(NB);
    dim3 gE((E + 255) / 256);

    // weight splits (independent, run first)
    k_wsplit<<<dim3(256), b256, 0, stream>>>(W1, wf1h, wf1l, 256, 256);
    k_wsplit<<<dim3(256), b256, 0, stream>>>(W2, wf2h, wf2l, 256, 256);
    k_wsplit<<<dim3(128), b256, 0, stream>>>(W3, wf3h, wf3l, 256, 128);
    k_wsplit<<<dim3(64),  b256, 0, stream>>>(P1, p1h, p1l, 128, 128);
    k_wsplit<<<dim3(64),  b256, 0, stream>>>(P2, p2h, p2l, 128, 128);

    // normalization + CSR build
    hipMemsetAsync(cnt, 0, (size_t)N * 4, stream);
    k_init_deg<<<gN, b256, 0, stream>>>(deg, N);
    k_edge_pass1<<<gE, b256, 0, stream>>>(edge_col, edge_val, deg, cnt, E);
    k_dinv<<<gN, b256, 0, stream>>>(deg, dinv, N);
    k_scan_blk<<<gN, b256, 0, stream>>>(cnt, cnt, bsum, N);
    k_scan_top<<<dim3(1), b256, 0, stream>>>(bsum, NB);
    k_scan_add<<<gN, b256, 0, stream>>>(cnt, bsum, rowptr, cur, N, E);
    k_scatter<<<gE, b256, 0, stream>>>(edge_row, edge_col, edge_val, dinv, cur, esrc, ew, E);

    const int gm128 = (N + 127) / 128;  // 391
    const int gm64  = (N + 63) / 64;    // 782

    // layer 1
    k_mm<128, 128, false><<<dim3(gm128, 2), dim3(256), 0, stream>>>(x, wf1h, wf1l, nullptr, bufA, N, 256, 256);
    k_agg<256, true><<<dim3(N), dim3(256), 0, stream>>>(bufA, rowptr, esrc, ew, dinv, b1, bufB);
    // layer 2
    k_mm<128, 128, false><<<dim3(gm128, 2), dim3(256), 0, stream>>>(bufB, wf2h, wf2l, nullptr, bufA, N, 256, 256);
    k_agg<256, true><<<dim3(N), dim3(256), 0, stream>>>(bufA, rowptr, esrc, ew, dinv, b2, bufB);
    // layer 3
    k_mm<64, 128, false><<<dim3(gm64, 1), dim3(128), 0, stream>>>(bufB, wf3h, wf3l, nullptr, bufA, N, 256, 128);
    k_agg<128, false><<<dim3(N), dim3(128), 0, stream>>>(bufA, rowptr, esrc, ew, dinv, b3, emb);
    // head
    k_mm<64, 128, true ><<<dim3(gm64, 1), dim3(128), 0, stream>>>(emb, p1h, p1l, pb1, bufA, N, 128, 128);
    k_mm<64, 128, false><<<dim3(gm64, 1), dim3(128), 0, stream>>>(bufA, p2h, p2l, pb2, z, N, 128, 128);
}